// Round 2
// baseline (57.727 us; speedup 1.0000x reference)
//
#include <hip/hip_runtime.h>

typedef _Float16 h2 __attribute__((ext_vector_type(2)));
typedef unsigned int uint32;

#define KCLS 20
#define NVAL 20
#define CDIM 64
#define HW   65536
#define NPIX (4*HW)

// ws / LDS table layout (bytes). Class strides chosen as multiples of 16 B
// with (stride/4)%32 == 4 so divergent-class LDS reads spread over 8 bank
// groups instead of colliding on banks 0-3.
#define KN_OFF      0
#define KN_KSTRIDE  2576          // 20 rows of 128 B (64 f16) + 16 pad
#define KN_BYTES    (KCLS*KN_KSTRIDE)            // 51520
#define VAL_OFF     KN_BYTES
#define VAL_KSTRIDE 3088          // 64 rows of 48 B (10 half2 + 8 pad) + 16 pad
#define VAL_BYTES   (KCLS*VAL_KSTRIDE)           // 61760
#define REST_OFF    (VAL_OFF + VAL_BYTES)        // 113280
#define REST_KSTRIDE 272          // 64 f32 + 16 pad
#define REST_BYTES  (KCLS*REST_KSTRIDE)          // 5440
#define TAB_BYTES   (REST_OFF + REST_BYTES)      // 118720
#define TAB_DWORDS  (TAB_BYTES/4)

static __device__ __forceinline__ h2 bch2(uint32 u) {
    return __builtin_bit_cast(h2, u);
}

// cvt_pkrtz returns __fp16v2 on this clang; bit_cast to our h2 (_Float16v2).
static __device__ __forceinline__ h2 pkrtz(float a, float b) {
    return __builtin_bit_cast(h2, __builtin_amdgcn_cvt_pkrtz(a, b));
}

static __device__ __forceinline__ float dot2acc(h2 a, h2 b, float acc) {
#if defined(__has_builtin)
#if __has_builtin(__builtin_amdgcn_fdot2)
    return __builtin_amdgcn_fdot2(a, b, acc, false);
#else
    return acc + (float)a[0]*(float)b[0] + (float)a[1]*(float)b[1];
#endif
#else
    return acc + (float)a[0]*(float)b[0] + (float)a[1]*(float)b[1];
#endif
}

// ---------------------------------------------------------------------------
// Prep: build f16 tables in ws.
//  threads [0,1280): (k,c) -> val2T row (j-pairs as half2) + rest[k][c]
//  threads [1280,1680): (k,j) -> normalized key column as f16 row (c-contig)
// ---------------------------------------------------------------------------
__global__ void prep_kernel(const float* __restrict__ key,
                            const float* __restrict__ val,
                            unsigned char* __restrict__ ws) {
    int i = blockIdx.x * 256 + threadIdx.x;
    if (i < KCLS*CDIM) {
        int k = i >> 6, c = i & 63;
        const float* vb = val + k*NVAL*CDIM + c;     // val[k][j][c]
        float v[NVAL];
        float s = 0.f;
        #pragma unroll
        for (int j = 0; j < NVAL; j++) { v[j] = vb[j*CDIM]; s += v[j]; }
        float t = 0.f;
        for (int kk = 0; kk < KCLS; kk++) {
            const float* vb2 = val + kk*NVAL*CDIM + c;
            #pragma unroll
            for (int j = 0; j < NVAL; j++) t += vb2[j*CDIM];
        }
        uint32* row = (uint32*)(ws + VAL_OFF + k*VAL_KSTRIDE + c*48);
        #pragma unroll
        for (int jp = 0; jp < 10; jp++) {
            h2 hh = pkrtz(v[2*jp], v[2*jp+1]);
            row[jp] = __builtin_bit_cast(uint32, hh);
        }
        row[10] = 0u; row[11] = 0u;
        *(float*)(ws + REST_OFF + k*REST_KSTRIDE + c*4) = (t - s) * (1.0f/NVAL);
    } else if (i < KCLS*CDIM + KCLS*NVAL) {
        int idx = i - KCLS*CDIM;
        int k = idx / NVAL, j = idx % NVAL;
        const float* kb = key + k*CDIM*NVAL + j;     // key[k][c][j]
        float x[CDIM];
        float ssq = 0.f;
        #pragma unroll
        for (int c = 0; c < CDIM; c++) { x[c] = kb[c*NVAL]; ssq = fmaf(x[c], x[c], ssq); }
        float inv = 1.0f / fmaxf(sqrtf(ssq), 1e-12f);
        uint32* row = (uint32*)(ws + KN_OFF + k*KN_KSTRIDE + j*128);
        #pragma unroll
        for (int cp = 0; cp < 32; cp++) {
            h2 hh = pkrtz(x[2*cp]*inv, x[2*cp+1]*inv);
            row[cp] = __builtin_bit_cast(uint32, hh);
        }
    }
}

// ---------------------------------------------------------------------------
// Main: 256 blocks x 1024 threads, one pixel per thread, tables in LDS.
// ---------------------------------------------------------------------------
__global__ __launch_bounds__(1024, 4) void main_kernel(
        const float* __restrict__ content, const int* __restrict__ seg,
        const unsigned char* __restrict__ tabs, float* __restrict__ out) {
    extern __shared__ unsigned char lds[];
    {
        const uint32* src = (const uint32*)tabs;
        uint32* dst = (uint32*)lds;
        for (int i = threadIdx.x; i < TAB_DWORDS; i += 1024) dst[i] = src[i];
    }
    __syncthreads();

    int gp = blockIdx.x * 1024 + threadIdx.x;      // 0..NPIX-1
    int b  = gp >> 16;
    int p  = gp & (HW - 1);
    int cls = seg[gp] + 1;

    const float* cptr = content + ((size_t)b * CDIM * HW) + p;
    float ssq = 0.f;
    h2 cn2[32];
    #pragma unroll
    for (int cp = 0; cp < 32; cp++) {
        float f0 = cptr[(size_t)(2*cp)   * HW];
        float f1 = cptr[(size_t)(2*cp+1) * HW];
        ssq = fmaf(f0, f0, ssq);
        ssq = fmaf(f1, f1, ssq);
        cn2[cp] = pkrtz(f0, f1);   // unnormalized; scale later
    }
    float inv = 1.0f / fmaxf(sqrtf(ssq), 1e-12f);

    // scores: sc[j] = <x, kn[cls][:,j]>  (f16 mul, f32 acc), scaled by inv after
    const unsigned char* knbase = lds + (size_t)cls * KN_KSTRIDE;
    float sc[20];
    #pragma unroll 4
    for (int j = 0; j < 20; j++) {
        const uint4* row = (const uint4*)(knbase + j*128);
        float a0 = 0.f, a1 = 0.f;
        #pragma unroll
        for (int q = 0; q < 8; q++) {
            uint4 v = row[q];
            a0 = dot2acc(cn2[4*q+0], bch2(v.x), a0);
            a1 = dot2acc(cn2[4*q+1], bch2(v.y), a1);
            a0 = dot2acc(cn2[4*q+2], bch2(v.z), a0);
            a1 = dot2acc(cn2[4*q+3], bch2(v.w), a1);
        }
        sc[j] = a0 + a1;
    }

    // softmax (scores are cosines in [-1,1]: no max-subtraction needed)
    float esum = 0.f;
    #pragma unroll
    for (int j = 0; j < 20; j++) { sc[j] = __expf(sc[j] * inv); esum += sc[j]; }
    float wscale = 1.0f / esum;
    h2 w2[10];
    #pragma unroll
    for (int jp = 0; jp < 10; jp++)
        w2[jp] = pkrtz(sc[2*jp] * wscale, sc[2*jp+1] * wscale);

    // PV: out[c] = rest[cls][c] + sum_j w[j]*val[cls][j][c]
    const unsigned char* vbase = lds + VAL_OFF + (size_t)cls * VAL_KSTRIDE;
    const float* rrow = (const float*)(lds + REST_OFF + (size_t)cls * REST_KSTRIDE);
    float* obase = out + ((size_t)b * CDIM * HW) + p;
    #pragma unroll 4
    for (int c = 0; c < 64; c++) {
        const unsigned char* vr = vbase + c*48;
        uint4 u0 = *(const uint4*)vr;
        uint4 u1 = *(const uint4*)(vr + 16);
        uint2 u2 = *(const uint2*)(vr + 32);
        float acc = rrow[c];
        acc = dot2acc(w2[0], bch2(u0.x), acc);
        acc = dot2acc(w2[1], bch2(u0.y), acc);
        acc = dot2acc(w2[2], bch2(u0.z), acc);
        acc = dot2acc(w2[3], bch2(u0.w), acc);
        acc = dot2acc(w2[4], bch2(u1.x), acc);
        acc = dot2acc(w2[5], bch2(u1.y), acc);
        acc = dot2acc(w2[6], bch2(u1.z), acc);
        acc = dot2acc(w2[7], bch2(u1.w), acc);
        acc = dot2acc(w2[8], bch2(u2.x), acc);
        acc = dot2acc(w2[9], bch2(u2.y), acc);
        obase[(size_t)c * HW] = acc;
    }
}

extern "C" void kernel_launch(void* const* d_in, const int* in_sizes, int n_in,
                              void* d_out, int out_size, void* d_ws, size_t ws_size,
                              hipStream_t stream) {
    const float* content = (const float*)d_in[0];
    const int*   seg     = (const int*)d_in[1];
    const float* key     = (const float*)d_in[2];
    const float* val     = (const float*)d_in[3];
    float* out = (float*)d_out;
    unsigned char* ws = (unsigned char*)d_ws;

    prep_kernel<<<7, 256, 0, stream>>>(key, val, ws);

    (void)hipFuncSetAttribute((const void*)main_kernel,
                              hipFuncAttributeMaxDynamicSharedMemorySize, TAB_BYTES);
    main_kernel<<<256, 1024, TAB_BYTES, stream>>>(content, seg, ws, out);
}